// Round 8
// baseline (22896.016 us; speedup 1.0000x reference)
//
#include <hip/hip_runtime.h>

#define BB 128   // batch
#define SS 128   // seq
#define EE 256   // enc dim
#define DD 256   // lstm hidden
#define OO 64    // out dim

// bf16 weight buffer layout (ushort offsets) inside d_out scratch
#define W1_OFF   0         // 768*256   = 196608 (rows: Wh|Wc|We)
#define WHH_OFF  196608    // 256*1024  = 262144
#define WIH_OFF  458752    // 64*1024   = 65536
#define FCW_OFF  524288    // 320*64    = 20480
#define WTOTAL   544768

__device__ __forceinline__ float fsig(float x) { return 1.0f / (1.0f + __expf(-x)); }
__device__ __forceinline__ float ftanh(float x) {
    float t = __expf(-2.0f * fabsf(x));
    float r = (1.0f - t) / (1.0f + t);
    return copysignf(r, x);
}
// swizzle within 32-float groups (rotate by 4*group): conflict-free strided reads in P2
__device__ __forceinline__ int SWZ(int e) { return (e & ~31) | ((e + 4 * (e >> 5)) & 31); }

__device__ __forceinline__ unsigned short bf16r(float f) {
    unsigned int u = __float_as_uint(f);
    u = (u + 0x7fffu + ((u >> 16) & 1u)) >> 16;
    return (unsigned short)u;
}
__device__ __forceinline__ float bflo(unsigned int x) { return __uint_as_float(x << 16); }
__device__ __forceinline__ float bfhi(unsigned int x) { return __uint_as_float(x & 0xffff0000u); }

__device__ __forceinline__ void fma8(const uint4 w, const float xv, float* acc) {
    acc[0] += xv * bflo(w.x); acc[1] += xv * bfhi(w.x);
    acc[2] += xv * bflo(w.y); acc[3] += xv * bfhi(w.y);
    acc[4] += xv * bflo(w.z); acc[5] += xv * bfhi(w.z);
    acc[6] += xv * bflo(w.w); acc[7] += xv * bfhi(w.w);
}

// fp32 -> bf16 (RNE) weight conversion, runs every launch (graph-safe, same work)
__global__ __launch_bounds__(256) void conv_kernel(
    const float* __restrict__ W1, const float* __restrict__ Whh,
    const float* __restrict__ Wih, const float* __restrict__ fcW,
    unsigned short* __restrict__ out)
{
    const int idx = blockIdx.x * 256 + threadIdx.x;
    float f;
    if      (idx < WHH_OFF)  f = W1[idx];
    else if (idx < WIH_OFF)  f = Whh[idx - WHH_OFF];
    else if (idx < FCW_OFF)  f = Wih[idx - WIH_OFF];
    else if (idx < WTOTAL)   f = fcW[idx - FCW_OFF];
    else return;
    out[idx] = bf16r(f);
}

// One block (512 thr, 8 waves) per batch row; whole scan block-local.
// __launch_bounds__(512,2) + LDS>80KB  =>  1 block/CU, 256-VGPR budget:
// weight loads issued in 16-deep uint4 batches (no spill at ~170 VGPRs).
__global__ __launch_bounds__(512, 2) void scan_kernel(
    const float* __restrict__ inp,   // B,S,E
    const float* __restrict__ yhist, // B,S,OO
    const float* __restrict__ h0, const float* __restrict__ c0,
    const float* __restrict__ W1f,   // fp32 W1 (only We rows used, init)
    const float* __restrict__ b1, const float* __restrict__ w2, const float* __restrict__ b2,
    const float* __restrict__ bih, const float* __restrict__ bhh,
    const float* __restrict__ fcb,
    const unsigned short* __restrict__ wbf,  // bf16 weights (see *_OFF)
    float* __restrict__ hctxT)       // ws: [512][128] (0..255 h, 256..511 ctx)
{
    __shared__ float red1[8192];     // 32 KB  P1 [16][256] / P3 [8][256] / P3b [32][64]
    __shared__ float red2[16384];    // 64 KB  P1b/P4 [4][1024]; init staging
    __shared__ float sh_h[DD], sh_c[DD], sh_hc[EE];  // sh_hc SWZ'd
    __shared__ float sh_gh[1024];
    __shared__ float sh_w2[EE];                      // SWZ'd
    __shared__ float sh_raw[SS];
    __shared__ float sh_ctx[EE], sh_yt[OO], sh_y[OO];
    // total ~106 KB: forces 1 block/CU so the VGPR budget is 256/thread

    const int b = blockIdx.x, t = threadIdx.x;
    const float* inp_b = inp + b * SS * EE;
    const unsigned short* W1bf  = wbf + W1_OFF;
    const unsigned short* Whhbf = wbf + WHH_OFF;
    const unsigned short* Wihbf = wbf + WIH_OFF;
    const unsigned short* fcWbf = wbf + FCW_OFF;
    const float b2v = b2[0];

    // per-thread constants
    const float b1_reg  = (t < 256) ? b1[t] : 0.f;
    const float fcb_reg = (t < 64) ? fcb[t] : 0.f;
    float bs4[4] = {0.f, 0.f, 0.f, 0.f};
    if (t < 256) {
        #pragma unroll
        for (int q = 0; q < 4; ++q) bs4[q] = bih[t + 256 * q] + bhh[t + 256 * q];
    }

    // role constants (512 threads)
    const int e8  = (t & 31) * 8,  kc1 = t >> 5;   // P1:  k in [kc1*32, +32)
    const int j8  = (t & 127) * 8, kcb = t >> 7;   // P1b: k in [kcb*64,+64); P4: [kcb*16,+16)
    const int s_own = t >> 2,      a4  = t & 3, e0 = a4 * 64;  // P2
    const int e4  = (t & 63) * 4,  sc  = t >> 6;   // P3:  s in [sc*16,+16)
    const int o4  = (t & 15) * 4,  kc3 = t >> 4;   // P3b: k in [kc3*10,+10)

    if (t < 256) {
        sh_h[t] = h0[b * 256 + t]; sh_c[t] = c0[b * 256 + t];
        sh_w2[SWZ(t)] = w2[t];
    }

    // ---- enc_proj into registers: er[j] = enc_proj[s_own][e0+j], j<64 ----
    float er[64];
    #pragma unroll
    for (int j = 0; j < 64; ++j) er[j] = 0.f;
    {
        float* stgW = red2;          // [16][256]
        float* stgI = red2 + 4096;   // [128][16]
        const float* We = W1f + 512 * 256;
        for (int kc = 0; kc < 16; ++kc) {
            {
                const int row = t >> 5, c8 = (t & 31) * 8;
                *(float4*)&stgW[row * 256 + c8] =
                    *(const float4*)(We + (size_t)(kc * 16 + row) * 256 + c8);
                *(float4*)&stgW[row * 256 + c8 + 4] =
                    *(const float4*)(We + (size_t)(kc * 16 + row) * 256 + c8 + 4);
            }
            {
                const int s = t >> 2, k4 = (t & 3) * 4;
                *(float4*)&stgI[s * 16 + k4] =
                    *(const float4*)(inp_b + s * 256 + kc * 16 + k4);
            }
            __syncthreads();
            for (int k = 0; k < 16; ++k) {
                const float xv = stgI[s_own * 16 + k];
                #pragma unroll
                for (int jj = 0; jj < 16; ++jj) {
                    float4 w = *(const float4*)&stgW[k * 256 + e0 + jj * 4];
                    er[jj*4+0] += xv * w.x; er[jj*4+1] += xv * w.y;
                    er[jj*4+2] += xv * w.z; er[jj*4+3] += xv * w.w;
                }
            }
            __syncthreads();
        }
    }

    for (int ts = 0; ts < SS; ++ts) {
        if (t < 64) sh_y[t] = yhist[b * SS * OO + ts * OO + t];

        // ---- P1: hc partials [16][256] -> red1 (2 batches of 16 uint4)
        {
            float acc[8];
            #pragma unroll
            for (int r = 0; r < 8; ++r) acc[r] = 0.f;
            #pragma unroll
            for (int hB = 0; hB < 2; ++hB) {
                uint4 w[16];
                #pragma unroll
                for (int i = 0; i < 16; ++i)
                    w[i] = *(const uint4*)(W1bf + (size_t)(kc1 * 32 + hB * 16 + i) * 256 + e8);
                #pragma unroll
                for (int i = 0; i < 16; ++i) {
                    const int k = kc1 * 32 + hB * 16 + i;
                    const float xv = (k < 256) ? sh_h[k] : sh_c[k - 256];
                    fma8(w[i], xv, acc);
                }
            }
            *(float4*)&red1[kc1 * 256 + e8]     = make_float4(acc[0], acc[1], acc[2], acc[3]);
            *(float4*)&red1[kc1 * 256 + e8 + 4] = make_float4(acc[4], acc[5], acc[6], acc[7]);
        }
        // ---- P1b: gh partials [4][1024] -> red2 (4 batches of 16 uint4)
        {
            float acc[8];
            #pragma unroll
            for (int r = 0; r < 8; ++r) acc[r] = 0.f;
            #pragma unroll
            for (int hB = 0; hB < 4; ++hB) {
                uint4 w[16];
                #pragma unroll
                for (int i = 0; i < 16; ++i)
                    w[i] = *(const uint4*)(Whhbf + (size_t)(kcb * 64 + hB * 16 + i) * 1024 + j8);
                #pragma unroll
                for (int i = 0; i < 16; ++i)
                    fma8(w[i], sh_h[kcb * 64 + hB * 16 + i], acc);
            }
            *(float4*)&red2[kcb * 1024 + j8]     = make_float4(acc[0], acc[1], acc[2], acc[3]);
            *(float4*)&red2[kcb * 1024 + j8 + 4] = make_float4(acc[4], acc[5], acc[6], acc[7]);
        }
        __syncthreads();   // B1

        // ---- reduce: hc (t<256), gh (all threads, 2 cols each)
        if (t < 256) {
            float v = b1_reg;
            #pragma unroll
            for (int kc = 0; kc < 16; ++kc) v += red1[kc * 256 + t];
            sh_hc[SWZ(t)] = v;
        }
        {
            float v0 = 0.f, v1 = 0.f;
            #pragma unroll
            for (int kc = 0; kc < 4; ++kc) {
                v0 += red2[kc * 1024 + t];
                v1 += red2[kc * 1024 + t + 512];
            }
            sh_gh[t] = v0; sh_gh[t + 512] = v1;
        }
        __syncthreads();   // B2

        // ---- P2: scores from er[64] + swizzled hc/w2 (conflict-free)
        {
            float acc = 0.f;
            #pragma unroll
            for (int jj = 0; jj < 16; ++jj) {
                const int eblk = e0 + jj * 4;
                const int phys = (eblk & ~31) | ((eblk + 4 * (eblk >> 5)) & 31);
                float4 hc4 = *(const float4*)&sh_hc[phys];
                float4 w24 = *(const float4*)&sh_w2[phys];
                acc += ftanh(er[jj*4+0] + hc4.x) * w24.x;
                acc += ftanh(er[jj*4+1] + hc4.y) * w24.y;
                acc += ftanh(er[jj*4+2] + hc4.z) * w24.z;
                acc += ftanh(er[jj*4+3] + hc4.w) * w24.w;
            }
            acc += __shfl_xor(acc, 1);
            acc += __shfl_xor(acc, 2);
            if (a4 == 0) sh_raw[s_own] = __expf(acc + b2v);  // max-free: |score|<=sum|w2|~10
        }
        __syncthreads();   // B3

        // ---- P3: context partials [8][256] -> red1 (global fp32 inp)
        {
            float ax = 0.f, ay = 0.f, az = 0.f, aw = 0.f;
            const float* ib = inp_b + sc * 16 * 256 + e4;
            #pragma unroll
            for (int s = 0; s < 16; ++s) {
                const float al = sh_raw[sc * 16 + s];
                float4 iv = *(const float4*)(ib + s * 256);
                ax += al * iv.x; ay += al * iv.y; az += al * iv.z; aw += al * iv.w;
            }
            *(float4*)&red1[sc * 256 + e4] = make_float4(ax, ay, az, aw);
        }
        __syncthreads();   // B4

        // ---- ctx reduce (t<256) with fused per-wave softmax denominator
        if (t < 256) {
            const int lane = t & 63;
            float sm = sh_raw[lane] + sh_raw[64 + lane];
            #pragma unroll
            for (int m = 32; m > 0; m >>= 1) sm += __shfl_xor(sm, m);
            const float rs = 1.0f / sm;
            float v = 0.f;
            #pragma unroll
            for (int k = 0; k < 8; ++k) v += red1[k * 256 + t];
            v *= rs;
            sh_ctx[t] = v;
            if (ts == SS - 1) hctxT[(size_t)(256 + t) * 128 + b] = v;
        }
        __syncthreads();   // B5

        // ---- P3b: y_tilde partials [32][64] -> red1 (10 uint2 in flight)
        {
            uint2 w[10];
            #pragma unroll
            for (int i = 0; i < 10; ++i)
                w[i] = *(const uint2*)(fcWbf + (kc3 * 10 + i) * 64 + o4);
            float acc[4] = {0.f, 0.f, 0.f, 0.f};
            #pragma unroll
            for (int i = 0; i < 10; ++i) {
                const int kk = kc3 * 10 + i;
                const float val = (kk < 256) ? sh_ctx[kk] : sh_y[kk - 256];
                acc[0] += val * bflo(w[i].x); acc[1] += val * bfhi(w[i].x);
                acc[2] += val * bflo(w[i].y); acc[3] += val * bfhi(w[i].y);
            }
            *(float4*)&red1[kc3 * 64 + o4] = make_float4(acc[0], acc[1], acc[2], acc[3]);
        }
        __syncthreads();   // B6

        if (t < 64) {
            float v = fcb_reg;
            #pragma unroll
            for (int kc = 0; kc < 32; ++kc) v += red1[kc * 64 + t];
            sh_yt[t] = v;
        }
        __syncthreads();   // B7

        // ---- P4: gate partials (Wih) [4][1024] -> red2 (16 uint4 in flight)
        {
            uint4 w[16];
            #pragma unroll
            for (int i = 0; i < 16; ++i)
                w[i] = *(const uint4*)(Wihbf + (size_t)(kcb * 16 + i) * 1024 + j8);
            float acc[8];
            #pragma unroll
            for (int r = 0; r < 8; ++r) acc[r] = 0.f;
            #pragma unroll
            for (int i = 0; i < 16; ++i)
                fma8(w[i], sh_yt[kcb * 16 + i], acc);
            *(float4*)&red2[kcb * 1024 + j8]     = make_float4(acc[0], acc[1], acc[2], acc[3]);
            *(float4*)&red2[kcb * 1024 + j8 + 4] = make_float4(acc[4], acc[5], acc[6], acc[7]);
        }
        __syncthreads();   // B8

        // ---- fused gates reduce + LSTM pointwise (t<256)
        if (t < 256) {
            float g[4];
            #pragma unroll
            for (int q = 0; q < 4; ++q) {
                float v = sh_gh[t + 256 * q] + bs4[q];
                #pragma unroll
                for (int kc = 0; kc < 4; ++kc) v += red2[kc * 1024 + t + 256 * q];
                g[q] = v;
            }
            const float cn = fsig(g[1]) * sh_c[t] + fsig(g[0]) * ftanh(g[2]);
            sh_c[t] = cn;
            const float hn = fsig(g[3]) * ftanh(cn);
            sh_h[t] = hn;
            if (ts == SS - 1) hctxT[(size_t)t * 128 + b] = hn;
        }
        __syncthreads();   // B9
    }
}

// out(128 x 8192) = A(128x512, stored transposed AT[512][128]) @ W(512x8192) + bias
__global__ __launch_bounds__(256) void out_gemm(
    const float* __restrict__ AT, const float* __restrict__ W,
    const float* __restrict__ bias, float* __restrict__ out)
{
    __shared__ float Ab[64 * 132];  // [k][m]
    __shared__ float Bb[64 * 32];   // [k][n]
    const int t = threadIdx.x;
    const int nt = blockIdx.x * 32;
    const int n4 = (t & 7) * 4;
    const int m4 = (t >> 3) * 4;
    float acc[4][4];
    #pragma unroll
    for (int i = 0; i < 4; ++i)
        #pragma unroll
        for (int jj = 0; jj < 4; ++jj) acc[i][jj] = 0.f;

    for (int kc = 0; kc < 8; ++kc) {
        #pragma unroll
        for (int i = 0; i < 8; ++i) {
            const int flat4 = i * 256 + t;
            const int row = flat4 >> 5, mm4 = (flat4 & 31) * 4;
            float4 v = *(const float4*)(AT + (size_t)(kc * 64 + row) * 128 + mm4);
            *(float4*)&Ab[row * 132 + mm4] = v;
        }
        #pragma unroll
        for (int i = 0; i < 2; ++i) {
            const int fl = t + i * 256;
            const int k = fl >> 3, nn4 = (fl & 7) * 4;
            *(float4*)&Bb[k * 32 + nn4] =
                *(const float4*)(W + (size_t)(kc * 64 + k) * 8192 + nt + nn4);
        }
        __syncthreads();
        for (int k = 0; k < 64; ++k) {
            const float4 bv = *(const float4*)&Bb[k * 32 + n4];
            const float4 av = *(const float4*)&Ab[k * 132 + m4];
            acc[0][0] += av.x * bv.x; acc[0][1] += av.x * bv.y; acc[0][2] += av.x * bv.z; acc[0][3] += av.x * bv.w;
            acc[1][0] += av.y * bv.x; acc[1][1] += av.y * bv.y; acc[1][2] += av.y * bv.z; acc[1][3] += av.y * bv.w;
            acc[2][0] += av.z * bv.x; acc[2][1] += av.z * bv.y; acc[2][2] += av.z * bv.z; acc[2][3] += av.z * bv.w;
            acc[3][0] += av.w * bv.x; acc[3][1] += av.w * bv.y; acc[3][2] += av.w * bv.z; acc[3][3] += av.w * bv.w;
        }
        __syncthreads();
    }
    const float4 bb = *(const float4*)(bias + nt + n4);
    #pragma unroll
    for (int i = 0; i < 4; ++i) {
        float4 r;
        r.x = acc[i][0] + bb.x; r.y = acc[i][1] + bb.y;
        r.z = acc[i][2] + bb.z; r.w = acc[i][3] + bb.w;
        *(float4*)(out + (size_t)(m4 + i) * 8192 + nt + n4) = r;
    }
}

extern "C" void kernel_launch(void* const* d_in, const int* in_sizes, int n_in,
                              void* d_out, int out_size, void* d_ws, size_t ws_size,
                              hipStream_t stream) {
    const float* inp = (const float*)d_in[0];
    const float* yh  = (const float*)d_in[1];
    const float* h0  = (const float*)d_in[2];
    const float* c0  = (const float*)d_in[3];
    const float* W1  = (const float*)d_in[4];
    const float* b1  = (const float*)d_in[5];
    const float* w2  = (const float*)d_in[6];
    const float* b2  = (const float*)d_in[7];
    const float* Wih = (const float*)d_in[8];
    const float* Whh = (const float*)d_in[9];
    const float* bih = (const float*)d_in[10];
    const float* bhh = (const float*)d_in[11];
    const float* fcW = (const float*)d_in[12];
    const float* fcb = (const float*)d_in[13];
    const float* foW = (const float*)d_in[14];
    const float* fob = (const float*)d_in[15];

    float* hctxT = (float*)d_ws;                    // 256 KB (proven)
    unsigned short* wbf = (unsigned short*)d_out;   // 1.09 MB bf16 weights in d_out scratch
                                                    // (fully overwritten by out_gemm)

    conv_kernel<<<dim3((WTOTAL + 255) / 256), dim3(256), 0, stream>>>(W1, Whh, Wih, fcW, wbf);
    scan_kernel<<<dim3(BB), dim3(512), 0, stream>>>(
        inp, yh, h0, c0, W1, b1, w2, b2, bih, bhh, fcb, wbf, hctxT);
    out_gemm<<<dim3(8192 / 32), dim3(256), 0, stream>>>(hctxT, foW, fob, (float*)d_out);
}